// Round 8
// baseline (22438.580 us; speedup 1.0000x reference)
//
#include <hip/hip_runtime.h>
#include <hip/hip_bf16.h>

// GRU-variant: B=64, T=512, D=L=1024.
// P layout: rows m = t*64+b, cols n: [0,1024)=gate_h x-part, [1024,2048)=gate_o
// x-part, [2048,3072)=qx.
// Recurrence: persistent kernel, 8 domains x 8 batches, domain d = blocks with
// bid%8==d (32 blocks, expected one per CU of XCD d under round-robin
// dispatch). Placement is VERIFIED at runtime (numeric-encoded s_getreg of
// XCC_ID + 256-block vote), then the L2 protocol is SMOKE-TESTED (one dry
// round with s_memrealtime timeout). Only if both pass does the fast path
// run: h exchange entirely in the XCD's L2 (sc0 stores/loads, L2-scope
// counter atomic + go-flag). Any failure -> all blocks take the round-3-
// verified fallback (sc0sc1 write-through h + agent-scope counter/go-flag
// through L3). Neither path can hang: fast is smoke-tested with timeout,
// fallback is the proven protocol.
// Sync-line discipline (r1/r2/r4): counter N writers 0 pollers; go-flag
// 1 writer many pollers. Raw barriers (lgkmcnt only, no vmcnt drain) keep
// P-prefetch/out-stores off the chain. Arrive-after-read (counter RMW ordered
// after each wave's vmcnt-tied A-read + both block barriers) keeps the
// double-buffered h race-free. MFMA A-tiles carry 8 valid rows (rows 8-15
// duplicate 0-7 via r&7, discarded by the q<2 Lred filter).

typedef __attribute__((ext_vector_type(4))) int   int4v;
typedef __attribute__((ext_vector_type(4))) short short4v;
typedef __attribute__((ext_vector_type(8))) short bf16x8;
typedef __attribute__((ext_vector_type(4))) float f32x4;

union Pack16 { int4v i; short4v s[2]; };
union FragU  { bf16x8 v; short4v s[2]; int4v i; };

__device__ __forceinline__ short f2bf(float f) {
  union { float f; unsigned u; } v; v.f = f;
  unsigned r = v.u + 0x7fffu + ((v.u >> 16) & 1u);
  return (short)(r >> 16);
}
__device__ __forceinline__ float bf2f(short s) {
  union { unsigned u; float f; } v; v.u = ((unsigned)(unsigned short)s) << 16;
  return v.f;
}

// LDS-only barrier: order LDS ops, do NOT drain vmcnt.
#define LDS_BARRIER()                                         \
  do {                                                        \
    asm volatile("s_waitcnt lgkmcnt(0)" ::: "memory");        \
    __builtin_amdgcn_s_barrier();                             \
    asm volatile("" ::: "memory");                            \
  } while (0)

// async global->LDS, 16B per lane.
__device__ __forceinline__ void gload_lds16(const short* g, short* l) {
  __builtin_amdgcn_global_load_lds(
      (const __attribute__((address_space(1))) void*)g,
      (__attribute__((address_space(3))) void*)l, 16, 0, 0);
}

// ---------------- prep kernels ----------------

__global__ __launch_bounds__(256) void cast_x_kernel(const float* __restrict__ xf,
                                                     short* __restrict__ xbf, int n4) {
  int i = blockIdx.x * 256 + threadIdx.x;
  if (i < n4) {
    float4 v = ((const float4*)xf)[i];
    short4v o;
    o.x = f2bf(v.x); o.y = f2bf(v.y); o.z = f2bf(v.z); o.w = f2bf(v.w);
    int r_in = i >> 8, c = i & 255;
    int b = r_in >> 9, t = r_in & 511;
    ((short4v*)xbf)[((t << 6) + b) * 256 + c] = o;
  }
}

__global__ __launch_bounds__(256) void transpose_cast(const float* __restrict__ src,
                                                      long ld, short* __restrict__ dst) {
  __shared__ float tile[64][65];
  const int n0 = blockIdx.x << 6, k0 = blockIdx.y << 6;
  const int c = threadIdx.x & 63, rr = threadIdx.x >> 6;
#pragma unroll 4
  for (int i = 0; i < 16; ++i)
    tile[i * 4 + rr][c] = src[(long)(k0 + i * 4 + rr) * ld + n0 + c];
  __syncthreads();
#pragma unroll 4
  for (int i = 0; i < 16; ++i)
    dst[(long)(n0 + i * 4 + rr) * 1024 + k0 + c] = f2bf(tile[c][i * 4 + rr]);
}

__global__ __launch_bounds__(256) void prep_misc(const float* __restrict__ wb,
                                                 const float* __restrict__ wxb,
                                                 const float* __restrict__ h0,
                                                 float* __restrict__ biasP,
                                                 short* __restrict__ hbf0) {
  int i = blockIdx.x * 256 + threadIdx.x;
  if (i < 65536) {
    hbf0[i] = f2bf(h0[i]);
  } else {
    int n = i - 65536;
    if (n < 3072) biasP[n] = (n < 2048) ? wb[n] : wxb[n - 2048];
  }
}

// ---------------- phase 1: P-GEMM (m97 structure) ----------------
__global__ __launch_bounds__(256) void pgemm_kernel(const short* __restrict__ A,
                                                    const short* __restrict__ Bt,
                                                    const float* __restrict__ biasP,
                                                    short* __restrict__ P) {
  __shared__ short As[128][32];
  __shared__ short Bs[128][32];
  const int tid = threadIdx.x;
  const int m0 = blockIdx.y << 7;
  const int n0 = blockIdx.x << 7;
  const int w = tid >> 6, lane = tid & 63;
  const int wm = w >> 1, wn = w & 1;
  const int q = lane >> 4, r = lane & 15;

  const int srow = (w << 5) + (lane >> 2);
  const int scol = (lane & 3) * 8;
  const short* gA0 = A  + (long)(m0 + srow) * 1024 + scol;
  const short* gA1 = gA0 + 16 * 1024;
  const short* gB0 = Bt + (long)(n0 + srow) * 1024 + scol;
  const short* gB1 = gB0 + 16 * 1024;
  short* lA0 = &As[(w << 5)][0];
  short* lA1 = &As[(w << 5) + 16][0];
  short* lB0 = &Bs[(w << 5)][0];
  short* lB1 = &Bs[(w << 5) + 16][0];

  const f32x4 zero = {0.f, 0.f, 0.f, 0.f};
  f32x4 acc[4][4];
#pragma unroll
  for (int a = 0; a < 4; ++a)
#pragma unroll
    for (int b = 0; b < 4; ++b) acc[a][b] = zero;

  for (int kk = 0; kk < 1024; kk += 32) {
    gload_lds16(gA0 + kk, lA0);
    gload_lds16(gA1 + kk, lA1);
    gload_lds16(gB0 + kk, lB0);
    gload_lds16(gB1 + kk, lB1);
    __syncthreads();

    FragU af[4], bfv[4];
#pragma unroll
    for (int mi = 0; mi < 4; ++mi)
      af[mi].i = *(const int4v*)&As[wm * 64 + mi * 16 + r][q * 8];
#pragma unroll
    for (int ni = 0; ni < 4; ++ni)
      bfv[ni].i = *(const int4v*)&Bs[wn * 64 + ni * 16 + r][q * 8];
#pragma unroll
    for (int mi = 0; mi < 4; ++mi)
#pragma unroll
      for (int ni = 0; ni < 4; ++ni)
        acc[mi][ni] = __builtin_amdgcn_mfma_f32_16x16x32_bf16(af[mi].v, bfv[ni].v,
                                                              acc[mi][ni], 0, 0, 0);
    __syncthreads();
  }

#pragma unroll
  for (int ni = 0; ni < 4; ++ni) {
    int gn = n0 + wn * 64 + ni * 16 + r;
    float bias = biasP[gn];
#pragma unroll
    for (int mi = 0; mi < 4; ++mi) {
      int gm = m0 + wm * 64 + mi * 16 + q * 4;
#pragma unroll
      for (int i = 0; i < 4; ++i)
        P[(long)(gm + i) * 3072 + gn] = f2bf(acc[mi][ni][i] + bias);
    }
  }
}

// ---------------- phase 2: persistent recurrence ----------------
// Grid 256 = 8 domains (dom=bid&7, 8 batches) x 32 col-blocks (slot, 32 j).
__global__ __launch_bounds__(256, 1) void recur_kernel(const short* __restrict__ RT,
                                                       const short* __restrict__ P,
                                                       const float* __restrict__ whb,
                                                       const float* __restrict__ h0,
                                                       short* __restrict__ hbuf,
                                                       float* __restrict__ out,
                                                       unsigned* __restrict__ sync) {
  __shared__ float Lred[4][6][256];
  __shared__ unsigned long long hstage_u[64];
  __shared__ unsigned fast_s;
  short* hstage = (short*)hstage_u;

  const int tid = threadIdx.x;
  const int bid = blockIdx.x;
  const int dom = bid & 7, slot = bid >> 3;
  const int w = tid >> 6, lane = tid & 63;
  const int q = lane >> 4, r = lane & 15;
  const int ks = w << 8;
  const f32x4 zero = {0.f, 0.f, 0.f, 0.f};

  unsigned* ctr = sync + dom * 32;        // main counter (N writers, 0 pollers)
  unsigned* gf  = sync + 256 + dom * 32;  // go-flag (1 writer, many pollers)

  // ---- placement vote + smoke test (hang-proof) ----
  if (tid == 0) {
    // XCC_ID via numeric getreg encoding (size32,off0,id20): garbage => safe fallback
    unsigned xcc = __builtin_amdgcn_s_getreg((31u << 11) | 20u);
    if ((xcc & 0xFu) != (unsigned)dom)
      __hip_atomic_fetch_or(sync + 512, 1u, __ATOMIC_RELAXED, __HIP_MEMORY_SCOPE_AGENT);
    asm volatile("s_waitcnt vmcnt(0)" ::: "memory");  // OR visible before arrival
    __hip_atomic_fetch_add(sync + 544, 1u, __ATOMIC_RELAXED, __HIP_MEMORY_SCOPE_AGENT);
    while (__hip_atomic_load(sync + 544, __ATOMIC_RELAXED, __HIP_MEMORY_SCOPE_AGENT) < 256u)
      __builtin_amdgcn_s_sleep(16);
    unsigned cand = (__hip_atomic_load(sync + 512, __ATOMIC_RELAXED,
                                       __HIP_MEMORY_SCOPE_AGENT) == 0u) ? 1u : 0u;
    if (cand) {  // cand is globally uniform: all 256 blocks run this together
      unsigned* sctr = sync + 576 + dom * 32;
      unsigned* sgf  = sync + 832 + dom * 32;
      unsigned old;
      asm volatile("global_atomic_add %0, %1, %2, off sc0\n\ts_waitcnt vmcnt(0)"
                   : "=v"(old) : "v"(sctr), "v"(1u) : "memory");
      if (old == 31u)
        asm volatile("global_store_dword %0, %1, off sc0" :: "v"(sgf), "v"(1u) : "memory");
      unsigned long long tb = __builtin_amdgcn_s_memrealtime();
      for (;;) {
        unsigned f;
        asm volatile("global_load_dword %0, %1, off sc0\n\ts_waitcnt vmcnt(0)"
                     : "=v"(f) : "v"(sgf) : "memory");
        if (f != 0u) break;
        if (__builtin_amdgcn_s_memrealtime() - tb > 2000000ull) {  // ~20ms
          __hip_atomic_fetch_or(sync + 1088, 1u, __ATOMIC_RELAXED,
                                __HIP_MEMORY_SCOPE_AGENT);
          asm volatile("s_waitcnt vmcnt(0)" ::: "memory");
          break;
        }
        __builtin_amdgcn_s_sleep(2);
      }
      __hip_atomic_fetch_add(sync + 1120, 1u, __ATOMIC_RELAXED, __HIP_MEMORY_SCOPE_AGENT);
      while (__hip_atomic_load(sync + 1120, __ATOMIC_RELAXED, __HIP_MEMORY_SCOPE_AGENT) < 256u)
        __builtin_amdgcn_s_sleep(16);
      fast_s = (__hip_atomic_load(sync + 1088, __ATOMIC_RELAXED,
                                  __HIP_MEMORY_SCOPE_AGENT) == 0u) ? 1u : 0u;
    } else {
      fast_s = 0u;
    }
  }
  __syncthreads();
  const bool fast = (fast_s != 0u);

  // B-frags: 6 n-tiles (3 gates x 2 col-halves) x 8 k-iters, register/AGPR.
  FragU Bf[6][8];
#pragma unroll
  for (int nt = 0; nt < 6; ++nt) {
    const int g = nt >> 1, ch = nt & 1;
    const long col = g * 1024 + slot * 32 + ch * 16 + r;
#pragma unroll
    for (int ki = 0; ki < 8; ++ki) {
      const short* p = RT + col * 1024 + ks + ki * 32 + q * 8;
      Pack16 t16; t16.i = *(const int4v*)p;
      Bf[nt][ki].s[0] = t16.s[0]; Bf[nt][ki].s[1] = t16.s[1];
    }
  }

  const int bl = tid >> 5, jl = tid & 31;
  float hp = h0[(long)(dom * 8 + bl) * 1024 + slot * 32 + jl];
  const float whbr = whb[slot * 32 + jl];
  const short* Pbase = P + (long)(dom * 8 + bl) * 3072 + slot * 32 + jl;
  short p0n = Pbase[0], p1n = Pbase[1024], p2n = Pbase[2048];  // t=0 prefetch
  const long outbase = (long)(dom * 8 + bl) * 512 * 1024 + slot * 32 + jl;

  for (int t = 0; t < 512; ++t) {
    const short* hcur = hbuf + (t & 1) * 65536;
    short* hnext = hbuf + ((t + 1) & 1) * 65536;

    // A-frags: 8 x 16B. fast: sc0 (bypass L1, read XCD-local L2 — all h
    // writers share this L2, no staleness). fallback: sc0 sc1 (L3, r3 path).
    const short* aptr = hcur + (dom * 8 + (r & 7)) * 1024 + ks + q * 8;
    FragU Af[8];
    if (fast) {
      asm volatile(
          "global_load_dwordx4 %0, %8, off sc0\n\t"
          "global_load_dwordx4 %1, %8, off offset:64 sc0\n\t"
          "global_load_dwordx4 %2, %8, off offset:128 sc0\n\t"
          "global_load_dwordx4 %3, %8, off offset:192 sc0\n\t"
          "global_load_dwordx4 %4, %8, off offset:256 sc0\n\t"
          "global_load_dwordx4 %5, %8, off offset:320 sc0\n\t"
          "global_load_dwordx4 %6, %8, off offset:384 sc0\n\t"
          "global_load_dwordx4 %7, %8, off offset:448 sc0\n\t"
          "s_waitcnt vmcnt(0)"
          : "=&v"(Af[0].i), "=&v"(Af[1].i), "=&v"(Af[2].i), "=&v"(Af[3].i),
            "=&v"(Af[4].i), "=&v"(Af[5].i), "=&v"(Af[6].i), "=&v"(Af[7].i)
          : "v"(aptr)
          : "memory");
    } else {
      asm volatile(
          "global_load_dwordx4 %0, %8, off sc0 sc1\n\t"
          "global_load_dwordx4 %1, %8, off offset:64 sc0 sc1\n\t"
          "global_load_dwordx4 %2, %8, off offset:128 sc0 sc1\n\t"
          "global_load_dwordx4 %3, %8, off offset:192 sc0 sc1\n\t"
          "global_load_dwordx4 %4, %8, off offset:256 sc0 sc1\n\t"
          "global_load_dwordx4 %5, %8, off offset:320 sc0 sc1\n\t"
          "global_load_dwordx4 %6, %8, off offset:384 sc0 sc1\n\t"
          "global_load_dwordx4 %7, %8, off offset:448 sc0 sc1\n\t"
          "s_waitcnt vmcnt(0)"
          : "=&v"(Af[0].i), "=&v"(Af[1].i), "=&v"(Af[2].i), "=&v"(Af[3].i),
            "=&v"(Af[4].i), "=&v"(Af[5].i), "=&v"(Af[6].i), "=&v"(Af[7].i)
          : "v"(aptr)
          : "memory");
    }

    // capture this step's P, prefetch t+1 (plain cached; full step to land)
    short c0 = p0n, c1 = p1n, c2 = p2n;
    if (t < 511) {
      const short* Pn = Pbase + (long)(t + 1) * 196608;
      p0n = Pn[0]; p1n = Pn[1024]; p2n = Pn[2048];
    }

    f32x4 acc[6];
#pragma unroll
    for (int nt = 0; nt < 6; ++nt) acc[nt] = zero;
#pragma unroll
    for (int ki = 0; ki < 8; ++ki)
#pragma unroll
      for (int nt = 0; nt < 6; ++nt)
        acc[nt] = __builtin_amdgcn_mfma_f32_16x16x32_bf16(Af[ki].v, Bf[nt][ki].v,
                                                          acc[nt], 0, 0, 0);

    // cross-wave K reduction. C/D: col=r, row=q*4+i; rows 0-7 valid (q<2).
    if (q < 2) {
#pragma unroll
      for (int nt = 0; nt < 6; ++nt)
#pragma unroll
        for (int i = 0; i < 4; ++i)
          Lred[w][nt][(q * 4 + i) * 16 + r] = acc[nt][i];
    }
    LDS_BARRIER();

    const int t0 = jl >> 4, e = bl * 16 + (jl & 15);
    float g0 = 0.f, g1 = 0.f, g2 = 0.f;
#pragma unroll
    for (int ww = 0; ww < 4; ++ww) {
      g0 += Lred[ww][t0][e];
      g1 += Lred[ww][2 + t0][e];
      g2 += Lred[ww][4 + t0][e];
    }

    float gh = 1.f / (1.f + __expf(-(bf2f(c0) + g0)));
    float go = 1.f / (1.f + __expf(-(bf2f(c1) + g1)));
    float mem = bf2f(c2) + gh * (g2 + whbr);
    float e2 = __expf(2.f * mem);
    float th = 1.f - 2.f / (e2 + 1.f);
    float hn = go * hp + (1.f - go) * th;
    hp = hn;
    out[outbase + (long)t * 1024] = hn;
    hstage[tid] = f2bf(hn);
    LDS_BARRIER();  // hstage visible to wave 0 (also: all Lred reads done)

    if (tid < 64) {  // wave 0: store h chunk (512B), drain, arrive
      unsigned long long hd = hstage_u[tid];
      short* hap = hnext + (dom * 8 + (tid >> 3)) * 1024 + slot * 32 + (tid & 7) * 4;
      if (fast)
        asm volatile("global_store_dwordx2 %0, %1, off sc0" :: "v"(hap), "v"(hd) : "memory");
      else
        asm volatile("global_store_dwordx2 %0, %1, off sc0 sc1" :: "v"(hap), "v"(hd) : "memory");
      asm volatile("s_waitcnt vmcnt(0)" ::: "memory");
      if (tid == 0) {
        if (fast) {  // L2-scope RMW + L2 go-flag
          unsigned old;
          asm volatile("global_atomic_add %0, %1, %2, off sc0\n\ts_waitcnt vmcnt(0)"
                       : "=v"(old) : "v"(ctr), "v"(1u) : "memory");
          if (old == 32u * (unsigned)(t + 1) - 1u)
            asm volatile("global_store_dword %0, %1, off sc0"
                         :: "v"(gf), "v"((unsigned)(t + 1)) : "memory");
        } else {
          unsigned old = __hip_atomic_fetch_add(ctr, 1u, __ATOMIC_RELAXED,
                                                __HIP_MEMORY_SCOPE_AGENT);
          if (old == 32u * (unsigned)(t + 1) - 1u)
            __hip_atomic_store(gf, (unsigned)(t + 1), __ATOMIC_RELAXED,
                               __HIP_MEMORY_SCOPE_AGENT);
        }
      }
    }
    // everyone polls the go-flag (fast: sc0/L2; fallback: agent/L3)
    if (fast) {
      for (;;) {
        unsigned f;
        asm volatile("global_load_dword %0, %1, off sc0\n\ts_waitcnt vmcnt(0)"
                     : "=v"(f) : "v"(gf) : "memory");
        if (f >= (unsigned)(t + 1)) break;
        __builtin_amdgcn_s_sleep(1);
      }
    } else {
      while (__hip_atomic_load(gf, __ATOMIC_RELAXED, __HIP_MEMORY_SCOPE_AGENT) <
             (unsigned)(t + 1))
        __builtin_amdgcn_s_sleep(1);
    }
  }
}

// ---------------- launch ----------------

extern "C" void kernel_launch(void* const* d_in, const int* in_sizes, int n_in,
                              void* d_out, int out_size, void* d_ws, size_t ws_size,
                              hipStream_t stream) {
  const float* x   = (const float*)d_in[0];  // [64][512][1024]
  const float* h0  = (const float*)d_in[1];  // [64][1024]
  const float* wW  = (const float*)d_in[2];  // [2048][2048]
  const float* wb  = (const float*)d_in[3];  // [2048]
  const float* wxW = (const float*)d_in[4];  // [1024][1024]
  const float* wxb = (const float*)d_in[5];  // [1024]
  const float* whW = (const float*)d_in[6];  // [1024][1024]
  const float* whb = (const float*)d_in[7];  // [1024]
  float* out = (float*)d_out;                // [64][512][1024]

  char* ws = (char*)d_ws;
  short*    P     = (short*)(ws);               // 201326592
  short*    xbf   = (short*)(ws + 201326592);   // 67108864
  short*    XwT   = (short*)(ws + 268435456);   // 6291456
  short*    RT    = (short*)(ws + 274726912);   // 6291456
  float*    biasP = (float*)(ws + 281018368);   // 12288
  short*    hbf   = (short*)(ws + 281030656);   // 262144 (2 buffers)
  unsigned* sync  = (unsigned*)(ws + 281292800);// 8192 (ctrs, flags, vote, smoke)

  hipMemsetAsync(sync, 0, 8192, stream);
  cast_x_kernel<<<dim3(32768), dim3(256), 0, stream>>>(x, xbf, 8388608);
  transpose_cast<<<dim3(32, 16), dim3(256), 0, stream>>>(wW, 2048, XwT);
  transpose_cast<<<dim3(16, 16), dim3(256), 0, stream>>>(wxW, 1024, XwT + 2048 * 1024);
  transpose_cast<<<dim3(32, 16), dim3(256), 0, stream>>>(wW + 1024 * 2048, 2048, RT);
  transpose_cast<<<dim3(16, 16), dim3(256), 0, stream>>>(whW, 1024, RT + 2048 * 1024);
  prep_misc<<<dim3(268), dim3(256), 0, stream>>>(wb, wxb, h0, biasP, hbf);
  pgemm_kernel<<<dim3(24, 256), dim3(256), 0, stream>>>(xbf, XwT, biasP, P);
  recur_kernel<<<dim3(256), dim3(256), 0, stream>>>(RT, P, whb, h0, hbf, out, sync);
}

// Round 9
// 2503.708 us; speedup vs baseline: 8.9621x; 8.9621x over previous
//
#include <hip/hip_runtime.h>
#include <hip/hip_bf16.h>

// GRU-variant: B=64, T=512, D=L=1024.
// P layout: rows m = t*64+b, cols n: [0,1024)=gate_h x-part, [1024,2048)=gate_o
// x-part, [2048,3072)=qx.
// Recurrence: persistent kernel, r3-verified L3 sync protocol (hot per-domain
// counter, threshold N*(t+1), never reset; go-flag 1 writer / all-wave
// pollers; sc0sc1 write-through h; raw lgkm-only barriers; arrive-after-read).
// r8 lesson: L2 is unusable as sync/exchange medium (both buffer_inv and
// XCD-local variants lose >=2.5x). This round keeps the protocol and attacks
// the two non-protocol terms:
//  (1) L3 A-burst: 512-thread blocks (8 waves = 4 K-slices x 2 col-halves),
//      32 blocks/domain; only cw==0 waves issue the global A-load, cw==1
//      waves get the frags from LDS (Ash) -> 8MB/step -> 4MB/step.
//  (2) counter RMW serialization: arrivals per domain 64 -> 32.

typedef __attribute__((ext_vector_type(4))) int   int4v;
typedef __attribute__((ext_vector_type(4))) short short4v;
typedef __attribute__((ext_vector_type(8))) short bf16x8;
typedef __attribute__((ext_vector_type(4))) float f32x4;

union Pack16 { int4v i; short4v s[2]; };
union FragU  { bf16x8 v; short4v s[2]; int4v i; };

__device__ __forceinline__ short f2bf(float f) {
  union { float f; unsigned u; } v; v.f = f;
  unsigned r = v.u + 0x7fffu + ((v.u >> 16) & 1u);
  return (short)(r >> 16);
}
__device__ __forceinline__ float bf2f(short s) {
  union { unsigned u; float f; } v; v.u = ((unsigned)(unsigned short)s) << 16;
  return v.f;
}

// LDS-only barrier: order LDS ops, do NOT drain vmcnt.
#define LDS_BARRIER()                                         \
  do {                                                        \
    asm volatile("s_waitcnt lgkmcnt(0)" ::: "memory");        \
    __builtin_amdgcn_s_barrier();                             \
    asm volatile("" ::: "memory");                            \
  } while (0)

// async global->LDS, 16B per lane.
__device__ __forceinline__ void gload_lds16(const short* g, short* l) {
  __builtin_amdgcn_global_load_lds(
      (const __attribute__((address_space(1))) void*)g,
      (__attribute__((address_space(3))) void*)l, 16, 0, 0);
}

// ---------------- prep kernels ----------------

__global__ __launch_bounds__(256) void cast_x_kernel(const float* __restrict__ xf,
                                                     short* __restrict__ xbf, int n4) {
  int i = blockIdx.x * 256 + threadIdx.x;
  if (i < n4) {
    float4 v = ((const float4*)xf)[i];
    short4v o;
    o.x = f2bf(v.x); o.y = f2bf(v.y); o.z = f2bf(v.z); o.w = f2bf(v.w);
    int r_in = i >> 8, c = i & 255;
    int b = r_in >> 9, t = r_in & 511;
    ((short4v*)xbf)[((t << 6) + b) * 256 + c] = o;
  }
}

__global__ __launch_bounds__(256) void transpose_cast(const float* __restrict__ src,
                                                      long ld, short* __restrict__ dst) {
  __shared__ float tile[64][65];
  const int n0 = blockIdx.x << 6, k0 = blockIdx.y << 6;
  const int c = threadIdx.x & 63, rr = threadIdx.x >> 6;
#pragma unroll 4
  for (int i = 0; i < 16; ++i)
    tile[i * 4 + rr][c] = src[(long)(k0 + i * 4 + rr) * ld + n0 + c];
  __syncthreads();
#pragma unroll 4
  for (int i = 0; i < 16; ++i)
    dst[(long)(n0 + i * 4 + rr) * 1024 + k0 + c] = f2bf(tile[c][i * 4 + rr]);
}

__global__ __launch_bounds__(256) void prep_misc(const float* __restrict__ wb,
                                                 const float* __restrict__ wxb,
                                                 const float* __restrict__ h0,
                                                 float* __restrict__ biasP,
                                                 short* __restrict__ hbf0) {
  int i = blockIdx.x * 256 + threadIdx.x;
  if (i < 65536) {
    hbf0[i] = f2bf(h0[i]);
  } else {
    int n = i - 65536;
    if (n < 3072) biasP[n] = (n < 2048) ? wb[n] : wxb[n - 2048];
  }
}

// ---------------- phase 1: P-GEMM (m97 structure, r5-verified) ----------------
__global__ __launch_bounds__(256) void pgemm_kernel(const short* __restrict__ A,
                                                    const short* __restrict__ Bt,
                                                    const float* __restrict__ biasP,
                                                    short* __restrict__ P) {
  __shared__ short As[128][32];
  __shared__ short Bs[128][32];
  const int tid = threadIdx.x;
  const int m0 = blockIdx.y << 7;
  const int n0 = blockIdx.x << 7;
  const int w = tid >> 6, lane = tid & 63;
  const int wm = w >> 1, wn = w & 1;
  const int q = lane >> 4, r = lane & 15;

  const int srow = (w << 5) + (lane >> 2);
  const int scol = (lane & 3) * 8;
  const short* gA0 = A  + (long)(m0 + srow) * 1024 + scol;
  const short* gA1 = gA0 + 16 * 1024;
  const short* gB0 = Bt + (long)(n0 + srow) * 1024 + scol;
  const short* gB1 = gB0 + 16 * 1024;
  short* lA0 = &As[(w << 5)][0];
  short* lA1 = &As[(w << 5) + 16][0];
  short* lB0 = &Bs[(w << 5)][0];
  short* lB1 = &Bs[(w << 5) + 16][0];

  const f32x4 zero = {0.f, 0.f, 0.f, 0.f};
  f32x4 acc[4][4];
#pragma unroll
  for (int a = 0; a < 4; ++a)
#pragma unroll
    for (int b = 0; b < 4; ++b) acc[a][b] = zero;

  for (int kk = 0; kk < 1024; kk += 32) {
    gload_lds16(gA0 + kk, lA0);
    gload_lds16(gA1 + kk, lA1);
    gload_lds16(gB0 + kk, lB0);
    gload_lds16(gB1 + kk, lB1);
    __syncthreads();

    FragU af[4], bfv[4];
#pragma unroll
    for (int mi = 0; mi < 4; ++mi)
      af[mi].i = *(const int4v*)&As[wm * 64 + mi * 16 + r][q * 8];
#pragma unroll
    for (int ni = 0; ni < 4; ++ni)
      bfv[ni].i = *(const int4v*)&Bs[wn * 64 + ni * 16 + r][q * 8];
#pragma unroll
    for (int mi = 0; mi < 4; ++mi)
#pragma unroll
      for (int ni = 0; ni < 4; ++ni)
        acc[mi][ni] = __builtin_amdgcn_mfma_f32_16x16x32_bf16(af[mi].v, bfv[ni].v,
                                                              acc[mi][ni], 0, 0, 0);
    __syncthreads();
  }

#pragma unroll
  for (int ni = 0; ni < 4; ++ni) {
    int gn = n0 + wn * 64 + ni * 16 + r;
    float bias = biasP[gn];
#pragma unroll
    for (int mi = 0; mi < 4; ++mi) {
      int gm = m0 + wm * 64 + mi * 16 + q * 4;
#pragma unroll
      for (int i = 0; i < 4; ++i)
        P[(long)(gm + i) * 3072 + gn] = f2bf(acc[mi][ni][i] + bias);
    }
  }
}

// ---------------- phase 2: persistent recurrence ----------------
// Grid 128 = 4 domains (bg = bid>>5, 16 batches) x 32 col-blocks (cg, 32 j).
// Block: 512 threads = 8 waves; wave (kw=w>>1, cw=w&1): K-slice kw*256,
// col-half cw*16. Only cw==0 waves load A from L3; cw==1 get it via Ash.
__global__ __launch_bounds__(512, 1) void recur_kernel(const short* __restrict__ RT,
                                                       const short* __restrict__ P,
                                                       const float* __restrict__ whb,
                                                       const float* __restrict__ h0,
                                                       short* __restrict__ hbuf,
                                                       float* __restrict__ out,
                                                       unsigned* __restrict__ sync) {
  __shared__ float Lred[4][6][256];   // [kw][gate*2+cw][batch*16+c]
  __shared__ short Ash[16384];        // [kw][ki][lane] 16B units, 32KB
  __shared__ short hstage[512];

  const int tid = threadIdx.x;
  const int bid = blockIdx.x;
  const int cg = bid & 31, bg = bid >> 5;
  const int w = tid >> 6, lane = tid & 63;
  const int kw = w >> 1, cw = w & 1;
  const int q = lane >> 4, r = lane & 15;
  const int ks = kw << 8;
  const f32x4 zero = {0.f, 0.f, 0.f, 0.f};

  // B-frags: 3 n-tiles (gate) x 8 k-iters for this wave's 16 cols / K-slice.
  FragU Bf[3][8];
#pragma unroll
  for (int nt = 0; nt < 3; ++nt) {
    const long col = nt * 1024 + cg * 32 + cw * 16 + r;
#pragma unroll
    for (int ki = 0; ki < 8; ++ki) {
      const short* p = RT + col * 1024 + ks + ki * 32 + q * 8;
      Pack16 t16; t16.i = *(const int4v*)p;
      Bf[nt][ki].s[0] = t16.s[0]; Bf[nt][ki].s[1] = t16.s[1];
    }
  }

  const int bl = tid >> 5, jl = tid & 31;       // batch row, col within 32
  float hp = h0[(long)(bg * 16 + bl) * 1024 + cg * 32 + jl];
  const float whbr = whb[cg * 32 + jl];
  const short* Pbase = P + (long)(bg * 16 + bl) * 3072 + cg * 32 + jl;
  short p0n = Pbase[0], p1n = Pbase[1024], p2n = Pbase[2048];  // t=0 prefetch
  const long outbase = (long)(bg * 16 + bl) * 512 * 1024 + cg * 32 + jl;

  unsigned* ctr = sync + bg * 32;        // hot counter line (never reset)
  unsigned* gf  = sync + 128 + bg * 32;  // go-flag, own 128B line

  for (int t = 0; t < 512; ++t) {
    const short* hcur = hbuf + (t & 1) * 65536;
    short* hnext = hbuf + ((t + 1) & 1) * 65536;

    // A-frags. cw==0: 8 x 16B sc0sc1 loads (bypass L1/L2, read L3) + tied
    // waitcnt — exact r3 pattern. cw==1: receives frags via Ash below.
    FragU Af[8];
    if (cw == 0) {
      const short* aptr = hcur + (bg * 16 + r) * 1024 + ks + q * 8;
      asm volatile(
          "global_load_dwordx4 %0, %8, off sc0 sc1\n\t"
          "global_load_dwordx4 %1, %8, off offset:64 sc0 sc1\n\t"
          "global_load_dwordx4 %2, %8, off offset:128 sc0 sc1\n\t"
          "global_load_dwordx4 %3, %8, off offset:192 sc0 sc1\n\t"
          "global_load_dwordx4 %4, %8, off offset:256 sc0 sc1\n\t"
          "global_load_dwordx4 %5, %8, off offset:320 sc0 sc1\n\t"
          "global_load_dwordx4 %6, %8, off offset:384 sc0 sc1\n\t"
          "global_load_dwordx4 %7, %8, off offset:448 sc0 sc1\n\t"
          "s_waitcnt vmcnt(0)"
          : "=&v"(Af[0].i), "=&v"(Af[1].i), "=&v"(Af[2].i), "=&v"(Af[3].i),
            "=&v"(Af[4].i), "=&v"(Af[5].i), "=&v"(Af[6].i), "=&v"(Af[7].i)
          : "v"(aptr)
          : "memory");
      // share with the cw==1 sibling wave (same kw): frag layout depends
      // only on (lane, ki, kw) — identical for both cw.
      short* dst = Ash + kw * 4096 + lane * 8;   // shorts: kw*4096 + ki*512 + lane*8
#pragma unroll
      for (int ki = 0; ki < 8; ++ki)
        *(int4v*)(dst + ki * 512) = Af[ki].i;
    }

    // capture this step's P, prefetch t+1 (plain cached; full step to land)
    short c0 = p0n, c1 = p1n, c2 = p2n;
    if (t < 511) {
      const short* Pn = Pbase + (long)(t + 1) * 196608;
      p0n = Pn[0]; p1n = Pn[1024]; p2n = Pn[2048];
    }

    LDS_BARRIER();  // Ash ready for cw==1

    if (cw == 1) {
      const short* src = Ash + kw * 4096 + lane * 8;
#pragma unroll
      for (int ki = 0; ki < 8; ++ki)
        Af[ki].i = *(const int4v*)(src + ki * 512);
    }

    f32x4 acc0 = zero, acc1 = zero, acc2 = zero;
#pragma unroll
    for (int ki = 0; ki < 8; ++ki) {
      acc0 = __builtin_amdgcn_mfma_f32_16x16x32_bf16(Af[ki].v, Bf[0][ki].v, acc0, 0, 0, 0);
      acc1 = __builtin_amdgcn_mfma_f32_16x16x32_bf16(Af[ki].v, Bf[1][ki].v, acc1, 0, 0, 0);
      acc2 = __builtin_amdgcn_mfma_f32_16x16x32_bf16(Af[ki].v, Bf[2][ki].v, acc2, 0, 0, 0);
    }

    // cross-wave K reduction. C/D: col=r, row=q*4+i.
#pragma unroll
    for (int i = 0; i < 4; ++i) {
      Lred[kw][0 + cw][(q * 4 + i) * 16 + r] = acc0[i];
      Lred[kw][2 + cw][(q * 4 + i) * 16 + r] = acc1[i];
      Lred[kw][4 + cw][(q * 4 + i) * 16 + r] = acc2[i];
    }
    LDS_BARRIER();

    const int cwi = jl >> 4, e = bl * 16 + (jl & 15);
    float g0 = 0.f, g1 = 0.f, g2 = 0.f;
#pragma unroll
    for (int kk = 0; kk < 4; ++kk) {
      g0 += Lred[kk][0 + cwi][e];
      g1 += Lred[kk][2 + cwi][e];
      g2 += Lred[kk][4 + cwi][e];
    }

    float gh = 1.f / (1.f + __expf(-(bf2f(c0) + g0)));
    float go = 1.f / (1.f + __expf(-(bf2f(c1) + g1)));
    float mem = bf2f(c2) + gh * (g2 + whbr);
    float e2 = __expf(2.f * mem);
    float th = 1.f - 2.f / (e2 + 1.f);
    float hn = go * hp + (1.f - go) * th;
    hp = hn;
    out[outbase + (long)t * 1024] = hn;
    hstage[tid] = f2bf(hn);
    LDS_BARRIER();  // hstage visible to wave 0 (also: all Lred reads done)

    if (tid < 64) {  // wave 0: write-through h chunk (1KB) to L3, drain, arrive
      int4v hd = *(const int4v*)&hstage[tid * 8];  // 16B = 8 h values
      short* hap = hnext + (bg * 16 + (tid >> 2)) * 1024 + cg * 32 + (tid & 3) * 8;
      asm volatile("global_store_dwordx4 %0, %1, off sc0 sc1"
                   :: "v"(hap), "v"(hd) : "memory");
      asm volatile("s_waitcnt vmcnt(0)" ::: "memory");
      if (tid == 0) {
        unsigned old = __hip_atomic_fetch_add(ctr, 1u, __ATOMIC_RELAXED,
                                              __HIP_MEMORY_SCOPE_AGENT);
        if (old == 32u * (unsigned)(t + 1) - 1u)
          __hip_atomic_store(gf, (unsigned)(t + 1), __ATOMIC_RELAXED,
                             __HIP_MEMORY_SCOPE_AGENT);
      }
    }
    // everyone polls the read-only go-flag (relaxed; no cache invalidates)
    while (__hip_atomic_load(gf, __ATOMIC_RELAXED, __HIP_MEMORY_SCOPE_AGENT) <
           (unsigned)(t + 1))
      __builtin_amdgcn_s_sleep(1);
  }
}

// ---------------- launch ----------------

extern "C" void kernel_launch(void* const* d_in, const int* in_sizes, int n_in,
                              void* d_out, int out_size, void* d_ws, size_t ws_size,
                              hipStream_t stream) {
  const float* x   = (const float*)d_in[0];  // [64][512][1024]
  const float* h0  = (const float*)d_in[1];  // [64][1024]
  const float* wW  = (const float*)d_in[2];  // [2048][2048]
  const float* wb  = (const float*)d_in[3];  // [2048]
  const float* wxW = (const float*)d_in[4];  // [1024][1024]
  const float* wxb = (const float*)d_in[5];  // [1024]
  const float* whW = (const float*)d_in[6];  // [1024][1024]
  const float* whb = (const float*)d_in[7];  // [1024]
  float* out = (float*)d_out;                // [64][512][1024]

  char* ws = (char*)d_ws;
  short*    P     = (short*)(ws);               // 201326592
  short*    xbf   = (short*)(ws + 201326592);   // 67108864
  short*    XwT   = (short*)(ws + 268435456);   // 6291456
  short*    RT    = (short*)(ws + 274726912);   // 6291456
  float*    biasP = (float*)(ws + 281018368);   // 12288
  short*    hbf   = (short*)(ws + 281030656);   // 262144 (2 buffers)
  unsigned* sync  = (unsigned*)(ws + 281292800);// 1024 (4 ctr lines + 4 flag lines)

  hipMemsetAsync(sync, 0, 1024, stream);
  cast_x_kernel<<<dim3(32768), dim3(256), 0, stream>>>(x, xbf, 8388608);
  transpose_cast<<<dim3(32, 16), dim3(256), 0, stream>>>(wW, 2048, XwT);
  transpose_cast<<<dim3(16, 16), dim3(256), 0, stream>>>(wxW, 1024, XwT + 2048 * 1024);
  transpose_cast<<<dim3(32, 16), dim3(256), 0, stream>>>(wW + 1024 * 2048, 2048, RT);
  transpose_cast<<<dim3(16, 16), dim3(256), 0, stream>>>(whW, 1024, RT + 2048 * 1024);
  prep_misc<<<dim3(268), dim3(256), 0, stream>>>(wb, wxb, h0, biasP, hbf);
  pgemm_kernel<<<dim3(24, 256), dim3(256), 0, stream>>>(xbf, XwT, biasP, P);
  recur_kernel<<<dim3(128), dim3(512), 0, stream>>>(RT, P, whb, h0, hbf, out, sync);
}